// Round 2
// baseline (1601.942 us; speedup 1.0000x reference)
//
#include <hip/hip_runtime.h>
#include <stdint.h>

#define N_TOK 16384
#define DIM   1024
#define HID   4096
#define NE    8
#define CAP   8192
#define MAXSLOT 33792   // sum of per-expert round_up128(kept) <= 32768 + 8*127
#define BM 128
#define BN 128
#define BK 32

typedef __attribute__((ext_vector_type(8))) __bf16 bf16x8;
typedef __attribute__((ext_vector_type(4))) float  f32x4;

__device__ inline unsigned short f2bf(float f) {
  unsigned u = __builtin_bit_cast(unsigned, f);
  u += 0x7fffu + ((u >> 16) & 1u);           // RNE
  return (unsigned short)(u >> 16);
}

__device__ inline void gload_lds16(const void* g, void* l) {
  __builtin_amdgcn_global_load_lds((__attribute__((address_space(1))) void*)(g),
                                   (__attribute__((address_space(3))) void*)(l),
                                   16, 0, 0);
}

// XCD swizzle: consecutive-dispatch blocks (f%8 fixed) share one XCD's L2.
// Groups all N-tiles of one M-strip onto the same XCD so the A strip is
// fetched once per XCD. Requires gridDim.x*gridDim.y % 8 == 0.
__device__ inline void xcd_remap(int& mtile, int& ntile) {
  int f = blockIdx.y * gridDim.x + blockIdx.x;
  int c = f & 7, q = f >> 3;
  int nT = gridDim.x;
  ntile = q % nT;
  mtile = (q / nT) * 8 + c;
}

// ---------------- router: logits, softmax, top-2, aux partial sums ----------
__global__ __launch_bounds__(256) void router_kernel(
    const float* __restrict__ x, const float* __restrict__ Wr, const float* __restrict__ br,
    int2* __restrict__ tokE, float2* __restrict__ tokW,
    float* __restrict__ probs_sum, int* __restrict__ mask_count)
{
  __shared__ float s_ps[NE];
  __shared__ int   s_mc[NE];
  int tid = threadIdx.x;
  if (tid < NE) { s_ps[tid] = 0.f; s_mc[tid] = 0; }
  __syncthreads();
  int wave = tid >> 6, lane = tid & 63;
  for (int i = 0; i < 2; ++i) {
    int token = blockIdx.x * 8 + wave * 2 + i;
    float acc[NE];
#pragma unroll
    for (int e = 0; e < NE; ++e) acc[e] = 0.f;
    const float* xr = x + (size_t)token * DIM;
#pragma unroll
    for (int j = 0; j < 4; ++j) {
      int d0 = j * 256 + lane * 4;
      float4 xv = *(const float4*)(xr + d0);
#pragma unroll
      for (int q = 0; q < 4; ++q) {
        float xs = (&xv.x)[q];
        const float* wr = Wr + (size_t)(d0 + q) * NE;
#pragma unroll
        for (int e = 0; e < NE; ++e) acc[e] += xs * wr[e];
      }
    }
#pragma unroll
    for (int ofs = 32; ofs >= 1; ofs >>= 1)
#pragma unroll
      for (int e = 0; e < NE; ++e) acc[e] += __shfl_xor(acc[e], ofs, 64);
    float m = -1e30f;
#pragma unroll
    for (int e = 0; e < NE; ++e) { acc[e] += br[e]; m = fmaxf(m, acc[e]); }
    float s = 0.f;
#pragma unroll
    for (int e = 0; e < NE; ++e) { acc[e] = __expf(acc[e] - m); s += acc[e]; }
    float inv = 1.f / s;
#pragma unroll
    for (int e = 0; e < NE; ++e) acc[e] *= inv;
    int e0 = 0; float p0 = acc[0];
#pragma unroll
    for (int e = 1; e < NE; ++e) if (acc[e] > p0) { p0 = acc[e]; e0 = e; }
    int e1 = -1; float p1 = -1.f;
#pragma unroll
    for (int e = 0; e < NE; ++e) if (e != e0 && acc[e] > p1) { p1 = acc[e]; e1 = e; }
    if (lane == 0) {
      tokE[token] = make_int2(e0, e1);
      tokW[token] = make_float2(p0, p1);
#pragma unroll
      for (int e = 0; e < NE; ++e) atomicAdd(&s_ps[e], acc[e]);
      atomicAdd(&s_mc[e0], 1); atomicAdd(&s_mc[e1], 1);
    }
  }
  __syncthreads();
  if (tid < NE) { atomicAdd(&probs_sum[tid], s_ps[tid]); atomicAdd(&mask_count[tid], s_mc[tid]); }
}

// ---------------- capacity scan: one wave per expert, ballot prefix --------
// Batched prefetch (8 chunks) to break the load-latency chain.
__global__ __launch_bounds__(512) void scan_kernel(
    const int2* __restrict__ tokE, const float2* __restrict__ tokW,
    const int* __restrict__ mask_count,
    int* __restrict__ offPad, int* __restrict__ slotTok, float* __restrict__ slotW)
{
  int wave = threadIdx.x >> 6, lane = threadIdx.x & 63;
  int eid = wave;
  int offs[NE + 1]; offs[0] = 0;
  int off = 0;
  for (int e = 0; e < NE; ++e) {
    int kept = min(mask_count[e], CAP);
    if (e == eid) off = offs[e];
    offs[e + 1] = offs[e] + ((kept + 127) & ~127);
  }
  if (wave == 0 && lane <= NE) offPad[lane] = offs[lane];
  int running = 0;
  for (int base = 0; base < N_TOK; base += 512) {
    int2 e2a[8]; float2 w2a[8];
#pragma unroll
    for (int u = 0; u < 8; ++u) {
      int t = base + u * 64 + lane;
      e2a[u] = tokE[t]; w2a[u] = tokW[t];
    }
#pragma unroll
    for (int u = 0; u < 8; ++u) {
      int t = base + u * 64 + lane;
      bool match = (e2a[u].x == eid) || (e2a[u].y == eid);
      float wgt = (e2a[u].x == eid) ? w2a[u].x : w2a[u].y;
      unsigned long long bal = __ballot(match);
      int pre = __popcll(bal & ((1ull << lane) - 1ull));
      if (match) {
        int pos = running + pre;
        if (pos < CAP) { slotTok[off + pos] = t; slotW[off + pos] = wgt; }
      }
      running += __popcll(bal);
    }
  }
  int kept = min(running, CAP);
  int padded = (kept + 127) & ~127;
  for (int i = kept + lane; i < padded; i += 64) { slotTok[off + i] = 0; slotW[off + i] = 0.f; }
}

// ---------------- aux loss -------------------------------------------------
__global__ void aux_kernel(const float* __restrict__ probs_sum,
                           const int* __restrict__ mask_count, float* __restrict__ out_aux)
{
  if (threadIdx.x == 0 && blockIdx.x == 0) {
    float bal = 0.f, imp = 0.f;
    for (int e = 0; e < NE; ++e) {
      float ps = probs_sum[e];
      bal += (ps / N_TOK) * ((float)mask_count[e] / N_TOK);
      imp += ps * ps;
    }
    out_aux[0] = bal * NE + imp / NE;
  }
}

// ---------------- gather kept tokens into compact bf16 Xg ------------------
__global__ __launch_bounds__(256) void gather_kernel(
    const float* __restrict__ x, const int* __restrict__ slotTok,
    const int* __restrict__ offPad, unsigned short* __restrict__ Xg)
{
  int total = offPad[NE];
  int wave = threadIdx.x >> 6, lane = threadIdx.x & 63;
  int slot = blockIdx.x * 4 + wave;
  if (slot >= total) return;
  int token = slotTok[slot];
  const float* src = x + (size_t)token * DIM;
  unsigned short* dst = Xg + (size_t)slot * DIM;
#pragma unroll
  for (int j = 0; j < 4; ++j) {
    int idx = j * 256 + lane * 4;
    float4 v = *(const float4*)(src + idx);
    ushort4 o;
    o.x = f2bf(v.x); o.y = f2bf(v.y); o.z = f2bf(v.z); o.w = f2bf(v.w);
    *(ushort4*)(dst + idx) = o;
  }
}

// ---------------- transpose + fp32->bf16: src[E][R][C] -> dst[E][C][R] -----
__global__ __launch_bounds__(256) void transpose_cvt(
    const float* __restrict__ src, unsigned short* __restrict__ dst, int R, int C)
{
  __shared__ float tile[64][65];
  int e = blockIdx.z;
  int cb = blockIdx.x * 64, rb = blockIdx.y * 64;
  int tid = threadIdx.x;
  int tr = tid >> 6, tc = tid & 63;
  const float* s = src + (size_t)e * R * C;
  unsigned short* d = dst + (size_t)e * R * C;
#pragma unroll
  for (int it = 0; it < 16; ++it) {
    int r = it * 4 + tr;
    tile[r][tc] = s[(size_t)(rb + r) * C + cb + tc];
  }
  __syncthreads();
#pragma unroll
  for (int it = 0; it < 16; ++it) {
    int r = it * 4 + tr;
    d[(size_t)(cb + r) * R + rb + tc] = f2bf(tile[tc][r]);
  }
}

// ---------------- GEMM1: H = relu(Xg @ W1 + b1), bf16 out ------------------
// Double-buffered LDS pipeline: stage k+1 overlaps MFMA of k. One barrier/iter.
__global__ __launch_bounds__(256) void gemm1_kernel(
    const unsigned short* __restrict__ Xg, const unsigned short* __restrict__ W1t,
    const float* __restrict__ b1, const int* __restrict__ offPad,
    unsigned short* __restrict__ Hbuf, int eBase, int compactH)
{
  int e = eBase + blockIdx.z;
  int off = offPad[e];
  int mtiles = (offPad[e + 1] - off) >> 7;
  int mtile, ntile;
  xcd_remap(mtile, ntile);
  if (mtile >= mtiles) return;
  int row0 = off + mtile * BM;
  int col0 = ntile * BN;
  int hrow0 = compactH ? row0 : mtile * BM;

  __shared__ alignas(16) unsigned short As[2][BM * BK];
  __shared__ alignas(16) unsigned short Bs[2][BN * BK];

  int tid = threadIdx.x;
  int wave = tid >> 6, lane = tid & 63;
  const unsigned short* Aptr = Xg + (size_t)row0 * DIM;
  const unsigned short* Bptr = W1t + (size_t)e * HID * DIM + (size_t)col0 * DIM;
  int ldRow = tid >> 2, ldCol = (tid & 3) * 8;

  f32x4 acc[4][4];
#pragma unroll
  for (int i = 0; i < 4; ++i)
#pragma unroll
    for (int j = 0; j < 4; ++j) acc[i][j] = f32x4{0.f, 0.f, 0.f, 0.f};

  int wm = (wave & 1) * 64, wn = (wave >> 1) * 64;
  int quad = lane >> 4, r16 = lane & 15;

  auto stage = [&](int buf, int kb) {
#pragma unroll
    for (int r = 0; r < 2; ++r) {
      gload_lds16(Aptr + (size_t)(r * 64 + ldRow) * DIM + kb + ldCol, &As[buf][wave * 512 + r * 2048]);
      gload_lds16(Bptr + (size_t)(r * 64 + ldRow) * DIM + kb + ldCol, &Bs[buf][wave * 512 + r * 2048]);
    }
  };

  stage(0, 0);
  for (int kb = 0; kb < DIM; kb += BK) {
    int cur = (kb >> 5) & 1;
    asm volatile("s_waitcnt vmcnt(0)" ::: "memory");
    __syncthreads();
    if (kb + BK < DIM) stage(cur ^ 1, kb + BK);
    bf16x8 af[4], bfr[4];
#pragma unroll
    for (int i = 0; i < 4; ++i) af[i]  = *reinterpret_cast<const bf16x8*>(&As[cur][(wm + i * 16 + r16) * BK + quad * 8]);
#pragma unroll
    for (int j = 0; j < 4; ++j) bfr[j] = *reinterpret_cast<const bf16x8*>(&Bs[cur][(wn + j * 16 + r16) * BK + quad * 8]);
#pragma unroll
    for (int i = 0; i < 4; ++i)
#pragma unroll
      for (int j = 0; j < 4; ++j)
        acc[i][j] = __builtin_amdgcn_mfma_f32_16x16x32_bf16(af[i], bfr[j], acc[i][j], 0, 0, 0);
  }
#pragma unroll
  for (int j = 0; j < 4; ++j) {
    int gc = col0 + wn + j * 16 + r16;
    float bias = b1[(size_t)e * HID + gc];
#pragma unroll
    for (int i = 0; i < 4; ++i)
#pragma unroll
      for (int r = 0; r < 4; ++r) {
        int lr = wm + i * 16 + quad * 4 + r;
        float v = fmaxf(acc[i][j][r] + bias, 0.f);
        Hbuf[(size_t)(hrow0 + lr) * HID + gc] = f2bf(v);
      }
  }
}

// ---------------- GEMM2: out = (H @ W2 + b2) * w, scatter-add --------------
__global__ __launch_bounds__(256) void gemm2_kernel(
    const unsigned short* __restrict__ Hbuf, const unsigned short* __restrict__ W2t,
    const float* __restrict__ b2, const int* __restrict__ offPad,
    const int* __restrict__ slotTok, const float* __restrict__ slotW,
    float* __restrict__ outF, int eBase, int compactH)
{
  int e = eBase + blockIdx.z;
  int off = offPad[e];
  int mtiles = (offPad[e + 1] - off) >> 7;
  int mtile, ntile;
  xcd_remap(mtile, ntile);
  if (mtile >= mtiles) return;
  int row0 = off + mtile * BM;
  int col0 = ntile * BN;
  int hrow0 = compactH ? row0 : mtile * BM;

  __shared__ alignas(16) unsigned short As[2][BM * BK];
  __shared__ alignas(16) unsigned short Bs[2][BN * BK];
  __shared__ int   sTok[BM];
  __shared__ float sW[BM];

  int tid = threadIdx.x;
  int wave = tid >> 6, lane = tid & 63;
  const unsigned short* Aptr = Hbuf + (size_t)hrow0 * HID;
  const unsigned short* Bptr = W2t + (size_t)e * DIM * HID + (size_t)col0 * HID;
  int ldRow = tid >> 2, ldCol = (tid & 3) * 8;

  f32x4 acc[4][4];
#pragma unroll
  for (int i = 0; i < 4; ++i)
#pragma unroll
    for (int j = 0; j < 4; ++j) acc[i][j] = f32x4{0.f, 0.f, 0.f, 0.f};

  int wm = (wave & 1) * 64, wn = (wave >> 1) * 64;
  int quad = lane >> 4, r16 = lane & 15;

  auto stage = [&](int buf, int kb) {
#pragma unroll
    for (int r = 0; r < 2; ++r) {
      gload_lds16(Aptr + (size_t)(r * 64 + ldRow) * HID + kb + ldCol, &As[buf][wave * 512 + r * 2048]);
      gload_lds16(Bptr + (size_t)(r * 64 + ldRow) * HID + kb + ldCol, &Bs[buf][wave * 512 + r * 2048]);
    }
  };

  if (tid < BM) { sTok[tid] = slotTok[row0 + tid]; sW[tid] = slotW[row0 + tid]; }

  stage(0, 0);
  for (int kb = 0; kb < HID; kb += BK) {
    int cur = (kb >> 5) & 1;
    asm volatile("s_waitcnt vmcnt(0)" ::: "memory");
    __syncthreads();
    if (kb + BK < HID) stage(cur ^ 1, kb + BK);
    bf16x8 af[4], bfr[4];
#pragma unroll
    for (int i = 0; i < 4; ++i) af[i]  = *reinterpret_cast<const bf16x8*>(&As[cur][(wm + i * 16 + r16) * BK + quad * 8]);
#pragma unroll
    for (int j = 0; j < 4; ++j) bfr[j] = *reinterpret_cast<const bf16x8*>(&Bs[cur][(wn + j * 16 + r16) * BK + quad * 8]);
#pragma unroll
    for (int i = 0; i < 4; ++i)
#pragma unroll
      for (int j = 0; j < 4; ++j)
        acc[i][j] = __builtin_amdgcn_mfma_f32_16x16x32_bf16(af[i], bfr[j], acc[i][j], 0, 0, 0);
  }
#pragma unroll
  for (int j = 0; j < 4; ++j) {
    int gc = col0 + wn + j * 16 + r16;
    float bias = b2[(size_t)e * DIM + gc];
#pragma unroll
    for (int i = 0; i < 4; ++i)
#pragma unroll
      for (int r = 0; r < 4; ++r) {
        int lr = wm + i * 16 + quad * 4 + r;
        float v = (acc[i][j][r] + bias) * sW[lr];
        atomicAdd(&outF[(size_t)sTok[lr] * DIM + gc], v);
      }
  }
}

extern "C" void kernel_launch(void* const* d_in, const int* in_sizes, int n_in,
                              void* d_out, int out_size, void* d_ws, size_t ws_size,
                              hipStream_t stream)
{
  const float* x  = (const float*)d_in[0];
  const float* Wr = (const float*)d_in[1];
  const float* br = (const float*)d_in[2];
  const float* W1 = (const float*)d_in[3];
  const float* b1 = (const float*)d_in[4];
  const float* W2 = (const float*)d_in[5];
  const float* b2 = (const float*)d_in[6];
  float* outF = (float*)d_out;

  char* ws = (char*)d_ws;
  size_t off = 0;
  auto alloc = [&](size_t bytes) -> char* {
    char* p = ws + off; off += (bytes + 255) & ~(size_t)255; return p;
  };
  char* meta = alloc(4096);
  float* probs_sum = (float*)meta;
  int*   mask_count = (int*)(meta + 64);
  int*   offPad = (int*)(meta + 128);
  int2*  tokE = (int2*)alloc((size_t)N_TOK * 8);
  float2* tokW = (float2*)alloc((size_t)N_TOK * 8);
  int*   slotTok = (int*)alloc((size_t)MAXSLOT * 4);
  float* slotW = (float*)alloc((size_t)MAXSLOT * 4);
  unsigned short* Xg  = (unsigned short*)alloc((size_t)MAXSLOT * DIM * 2);
  unsigned short* W1t = (unsigned short*)alloc((size_t)NE * HID * DIM * 2);
  unsigned short* W2t = (unsigned short*)alloc((size_t)NE * DIM * HID * 2);
  size_t hFull = (size_t)MAXSLOT * HID * 2;
  size_t hOne  = (size_t)CAP * HID * 2;
  bool compact = (off + hFull) <= ws_size;
  unsigned short* Hbuf = (unsigned short*)alloc(compact ? hFull : hOne);

  hipMemsetAsync(meta, 0, 4096, stream);
  hipMemsetAsync(d_out, 0, (size_t)out_size * 4, stream);

  transpose_cvt<<<dim3(HID / 64, DIM / 64, NE), 256, 0, stream>>>(W1, W1t, DIM, HID);
  transpose_cvt<<<dim3(DIM / 64, HID / 64, NE), 256, 0, stream>>>(W2, W2t, HID, DIM);
  router_kernel<<<dim3(N_TOK / 8), 256, 0, stream>>>(x, Wr, br, tokE, tokW, probs_sum, mask_count);
  scan_kernel<<<dim3(1), 512, 0, stream>>>(tokE, tokW, mask_count, offPad, slotTok, slotW);
  aux_kernel<<<dim3(1), 64, 0, stream>>>(probs_sum, mask_count, outF + (size_t)N_TOK * DIM);
  gather_kernel<<<dim3(MAXSLOT / 4), 256, 0, stream>>>(x, slotTok, offPad, Xg);

  if (compact) {
    gemm1_kernel<<<dim3(HID / BN, CAP / BM, NE), 256, 0, stream>>>(Xg, W1t, b1, offPad, Hbuf, 0, 1);
    gemm2_kernel<<<dim3(DIM / BN, CAP / BM, NE), 256, 0, stream>>>(Hbuf, W2t, b2, offPad, slotTok, slotW, outF, 0, 1);
  } else {
    for (int e = 0; e < NE; ++e) {
      gemm1_kernel<<<dim3(HID / BN, CAP / BM, 1), 256, 0, stream>>>(Xg, W1t, b1, offPad, Hbuf, e, 0);
      gemm2_kernel<<<dim3(DIM / BN, CAP / BM, 1), 256, 0, stream>>>(Hbuf, W2t, b2, offPad, slotTok, slotW, outF, e, 0);
    }
  }
}

// Round 3
// 1343.403 us; speedup vs baseline: 1.1925x; 1.1925x over previous
//
#include <hip/hip_runtime.h>
#include <stdint.h>

#define N_TOK 16384
#define DIM   1024
#define HID   4096
#define NE    8
#define CAP   8192
#define MAXSLOT 33792   // sum of per-expert round_up128(kept) <= 32768 + 8*127
#define BM 128
#define BN 128
#define BK 32

typedef __attribute__((ext_vector_type(8))) __bf16 bf16x8;
typedef __attribute__((ext_vector_type(4))) float  f32x4;

__device__ inline unsigned short f2bf(float f) {
  unsigned u = __builtin_bit_cast(unsigned, f);
  u += 0x7fffu + ((u >> 16) & 1u);           // RNE
  return (unsigned short)(u >> 16);
}

__device__ inline void gload_lds16(const void* g, void* l) {
  __builtin_amdgcn_global_load_lds((__attribute__((address_space(1))) void*)(g),
                                   (__attribute__((address_space(3))) void*)(l),
                                   16, 0, 0);
}

// XCD swizzle: consecutive-dispatch blocks (f%8 fixed) share one XCD's L2.
__device__ inline void xcd_remap(int& mtile, int& ntile) {
  int f = blockIdx.y * gridDim.x + blockIdx.x;
  int c = f & 7, q = f >> 3;
  int nT = gridDim.x;
  ntile = q % nT;
  mtile = (q / nT) * 8 + c;
}

// LDS column swizzle: physical 8-elem slot c of row r holds global block
// (c - (r>>1)) & 3. Reader of logical block q uses slot (q + (r>>1)) & 3.
// Makes each bank hit exactly 2x per 16-lane phase (free, m136) instead of
// the 8-way conflict of the identity layout (row stride 64B = 16 banks).

// ---------------- router: logits, softmax, top-2, aux partial sums ----------
__global__ __launch_bounds__(256) void router_kernel(
    const float* __restrict__ x, const float* __restrict__ Wr, const float* __restrict__ br,
    int2* __restrict__ tokE, float2* __restrict__ tokW,
    float* __restrict__ probs_sum, int* __restrict__ mask_count)
{
  __shared__ float s_ps[NE];
  __shared__ int   s_mc[NE];
  int tid = threadIdx.x;
  if (tid < NE) { s_ps[tid] = 0.f; s_mc[tid] = 0; }
  __syncthreads();
  int wave = tid >> 6, lane = tid & 63;
  for (int i = 0; i < 2; ++i) {
    int token = blockIdx.x * 8 + wave * 2 + i;
    float acc[NE];
#pragma unroll
    for (int e = 0; e < NE; ++e) acc[e] = 0.f;
    const float* xr = x + (size_t)token * DIM;
#pragma unroll
    for (int j = 0; j < 4; ++j) {
      int d0 = j * 256 + lane * 4;
      float4 xv = *(const float4*)(xr + d0);
#pragma unroll
      for (int q = 0; q < 4; ++q) {
        float xs = (&xv.x)[q];
        const float* wr = Wr + (size_t)(d0 + q) * NE;
#pragma unroll
        for (int e = 0; e < NE; ++e) acc[e] += xs * wr[e];
      }
    }
#pragma unroll
    for (int ofs = 32; ofs >= 1; ofs >>= 1)
#pragma unroll
      for (int e = 0; e < NE; ++e) acc[e] += __shfl_xor(acc[e], ofs, 64);
    float m = -1e30f;
#pragma unroll
    for (int e = 0; e < NE; ++e) { acc[e] += br[e]; m = fmaxf(m, acc[e]); }
    float s = 0.f;
#pragma unroll
    for (int e = 0; e < NE; ++e) { acc[e] = __expf(acc[e] - m); s += acc[e]; }
    float inv = 1.f / s;
#pragma unroll
    for (int e = 0; e < NE; ++e) acc[e] *= inv;
    int e0 = 0; float p0 = acc[0];
#pragma unroll
    for (int e = 1; e < NE; ++e) if (acc[e] > p0) { p0 = acc[e]; e0 = e; }
    int e1 = -1; float p1 = -1.f;
#pragma unroll
    for (int e = 0; e < NE; ++e) if (e != e0 && acc[e] > p1) { p1 = acc[e]; e1 = e; }
    if (lane == 0) {
      tokE[token] = make_int2(e0, e1);
      tokW[token] = make_float2(p0, p1);
#pragma unroll
      for (int e = 0; e < NE; ++e) atomicAdd(&s_ps[e], acc[e]);
      atomicAdd(&s_mc[e0], 1); atomicAdd(&s_mc[e1], 1);
    }
  }
  __syncthreads();
  if (tid < NE) { atomicAdd(&probs_sum[tid], s_ps[tid]); atomicAdd(&mask_count[tid], s_mc[tid]); }
}

// ---------------- capacity scan: one wave per expert, ballot prefix --------
__global__ __launch_bounds__(512) void scan_kernel(
    const int2* __restrict__ tokE, const float2* __restrict__ tokW,
    const int* __restrict__ mask_count,
    int* __restrict__ offPad, int* __restrict__ slotTok, float* __restrict__ slotW)
{
  int wave = threadIdx.x >> 6, lane = threadIdx.x & 63;
  int eid = wave;
  int offs[NE + 1]; offs[0] = 0;
  int off = 0;
  for (int e = 0; e < NE; ++e) {
    int kept = min(mask_count[e], CAP);
    if (e == eid) off = offs[e];
    offs[e + 1] = offs[e] + ((kept + 127) & ~127);
  }
  if (wave == 0 && lane <= NE) offPad[lane] = offs[lane];
  int running = 0;
  for (int base = 0; base < N_TOK; base += 512) {
    int2 e2a[8]; float2 w2a[8];
#pragma unroll
    for (int u = 0; u < 8; ++u) {
      int t = base + u * 64 + lane;
      e2a[u] = tokE[t]; w2a[u] = tokW[t];
    }
#pragma unroll
    for (int u = 0; u < 8; ++u) {
      int t = base + u * 64 + lane;
      bool match = (e2a[u].x == eid) || (e2a[u].y == eid);
      float wgt = (e2a[u].x == eid) ? w2a[u].x : w2a[u].y;
      unsigned long long bal = __ballot(match);
      int pre = __popcll(bal & ((1ull << lane) - 1ull));
      if (match) {
        int pos = running + pre;
        if (pos < CAP) { slotTok[off + pos] = t; slotW[off + pos] = wgt; }
      }
      running += __popcll(bal);
    }
  }
  int kept = min(running, CAP);
  int padded = (kept + 127) & ~127;
  for (int i = kept + lane; i < padded; i += 64) { slotTok[off + i] = 0; slotW[off + i] = 0.f; }
}

// ---------------- aux loss -------------------------------------------------
__global__ void aux_kernel(const float* __restrict__ probs_sum,
                           const int* __restrict__ mask_count, float* __restrict__ out_aux)
{
  if (threadIdx.x == 0 && blockIdx.x == 0) {
    float bal = 0.f, imp = 0.f;
    for (int e = 0; e < NE; ++e) {
      float ps = probs_sum[e];
      bal += (ps / N_TOK) * ((float)mask_count[e] / N_TOK);
      imp += ps * ps;
    }
    out_aux[0] = bal * NE + imp / NE;
  }
}

// ---------------- gather kept tokens into compact bf16 Xg ------------------
__global__ __launch_bounds__(256) void gather_kernel(
    const float* __restrict__ x, const int* __restrict__ slotTok,
    const int* __restrict__ offPad, unsigned short* __restrict__ Xg)
{
  int total = offPad[NE];
  int wave = threadIdx.x >> 6, lane = threadIdx.x & 63;
  int slot = blockIdx.x * 4 + wave;
  if (slot >= total) return;
  int token = slotTok[slot];
  const float* src = x + (size_t)token * DIM;
  unsigned short* dst = Xg + (size_t)slot * DIM;
#pragma unroll
  for (int j = 0; j < 4; ++j) {
    int idx = j * 256 + lane * 4;
    float4 v = *(const float4*)(src + idx);
    ushort4 o;
    o.x = f2bf(v.x); o.y = f2bf(v.y); o.z = f2bf(v.z); o.w = f2bf(v.w);
    *(ushort4*)(dst + idx) = o;
  }
}

// ---------------- transpose + fp32->bf16: src[E][R][C] -> dst[E][C][R] -----
__global__ __launch_bounds__(256) void transpose_cvt(
    const float* __restrict__ src, unsigned short* __restrict__ dst, int R, int C)
{
  __shared__ float tile[64][65];
  int e = blockIdx.z;
  int cb = blockIdx.x * 64, rb = blockIdx.y * 64;
  int tid = threadIdx.x;
  int tr = tid >> 6, tc = tid & 63;
  const float* s = src + (size_t)e * R * C;
  unsigned short* d = dst + (size_t)e * R * C;
#pragma unroll
  for (int it = 0; it < 16; ++it) {
    int r = it * 4 + tr;
    tile[r][tc] = s[(size_t)(rb + r) * C + cb + tc];
  }
  __syncthreads();
#pragma unroll
  for (int it = 0; it < 16; ++it) {
    int r = it * 4 + tr;
    d[(size_t)(cb + r) * R + rb + tc] = f2bf(tile[tc][r]);
  }
}

// ---------------- GEMM1: H = relu(Xg @ W1 + b1), bf16 out ------------------
__global__ __launch_bounds__(256, 2) void gemm1_kernel(
    const unsigned short* __restrict__ Xg, const unsigned short* __restrict__ W1t,
    const float* __restrict__ b1, const int* __restrict__ offPad,
    unsigned short* __restrict__ Hbuf, int eBase, int compactH)
{
  int e = eBase + blockIdx.z;
  int off = offPad[e];
  int mtiles = (offPad[e + 1] - off) >> 7;
  int mtile, ntile;
  xcd_remap(mtile, ntile);
  if (mtile >= mtiles) return;
  int row0 = off + mtile * BM;
  int col0 = ntile * BN;
  int hrow0 = compactH ? row0 : mtile * BM;

  __shared__ alignas(16) unsigned short As[2][BM * BK];
  __shared__ alignas(16) unsigned short Bs[2][BN * BK];

  int tid = threadIdx.x;
  int wave = tid >> 6, lane = tid & 63;
  const unsigned short* Aptr = Xg + (size_t)row0 * DIM;
  const unsigned short* Bptr = W1t + (size_t)e * HID * DIM + (size_t)col0 * DIM;
  int ldRow = tid >> 2, ldC = tid & 3;

  f32x4 acc[4][4];
#pragma unroll
  for (int i = 0; i < 4; ++i)
#pragma unroll
    for (int j = 0; j < 4; ++j) acc[i][j] = f32x4{0.f, 0.f, 0.f, 0.f};

  int wm = (wave & 1) * 64, wn = (wave >> 1) * 64;
  int quad = lane >> 4, r16 = lane & 15;

  auto stage = [&](int buf, int kb) {
#pragma unroll
    for (int r = 0; r < 2; ++r) {
      int row = r * 64 + ldRow;
      int gcol = kb + ((ldC - (row >> 1)) & 3) * 8;   // column swizzle
      gload_lds16(Aptr + (size_t)row * DIM + gcol, &As[buf][wave * 512 + r * 2048]);
      gload_lds16(Bptr + (size_t)row * DIM + gcol, &Bs[buf][wave * 512 + r * 2048]);
    }
  };

  stage(0, 0);
  for (int kb = 0; kb < DIM; kb += BK) {
    int cur = (kb >> 5) & 1;
    asm volatile("s_waitcnt vmcnt(0)" ::: "memory");
    __syncthreads();
    if (kb + BK < DIM) stage(cur ^ 1, kb + BK);
    bf16x8 af[4], bfr[4];
#pragma unroll
    for (int i = 0; i < 4; ++i) {
      int row = wm + i * 16 + r16;
      af[i] = *reinterpret_cast<const bf16x8*>(&As[cur][row * BK + ((quad + (row >> 1)) & 3) * 8]);
    }
#pragma unroll
    for (int j = 0; j < 4; ++j) {
      int row = wn + j * 16 + r16;
      bfr[j] = *reinterpret_cast<const bf16x8*>(&Bs[cur][row * BK + ((quad + (row >> 1)) & 3) * 8]);
    }
#pragma unroll
    for (int i = 0; i < 4; ++i)
#pragma unroll
      for (int j = 0; j < 4; ++j)
        acc[i][j] = __builtin_amdgcn_mfma_f32_16x16x32_bf16(af[i], bfr[j], acc[i][j], 0, 0, 0);
  }
#pragma unroll
  for (int j = 0; j < 4; ++j) {
    int gc = col0 + wn + j * 16 + r16;
    float bias = b1[(size_t)e * HID + gc];
#pragma unroll
    for (int i = 0; i < 4; ++i)
#pragma unroll
      for (int r = 0; r < 4; ++r) {
        int lr = wm + i * 16 + quad * 4 + r;
        float v = fmaxf(acc[i][j][r] + bias, 0.f);
        Hbuf[(size_t)(hrow0 + lr) * HID + gc] = f2bf(v);
      }
  }
}

// ---------------- GEMM2: out = (H @ W2 + b2) * w, scatter-add --------------
__global__ __launch_bounds__(256, 2) void gemm2_kernel(
    const unsigned short* __restrict__ Hbuf, const unsigned short* __restrict__ W2t,
    const float* __restrict__ b2, const int* __restrict__ offPad,
    const int* __restrict__ slotTok, const float* __restrict__ slotW,
    float* __restrict__ outF, int eBase, int compactH)
{
  int e = eBase + blockIdx.z;
  int off = offPad[e];
  int mtiles = (offPad[e + 1] - off) >> 7;
  int mtile, ntile;
  xcd_remap(mtile, ntile);
  if (mtile >= mtiles) return;
  int row0 = off + mtile * BM;
  int col0 = ntile * BN;
  int hrow0 = compactH ? row0 : mtile * BM;

  __shared__ alignas(16) unsigned short As[2][BM * BK];
  __shared__ alignas(16) unsigned short Bs[2][BN * BK];
  __shared__ int   sTok[BM];
  __shared__ float sW[BM];

  int tid = threadIdx.x;
  int wave = tid >> 6, lane = tid & 63;
  const unsigned short* Aptr = Hbuf + (size_t)hrow0 * HID;
  const unsigned short* Bptr = W2t + (size_t)e * DIM * HID + (size_t)col0 * HID;
  int ldRow = tid >> 2, ldC = tid & 3;

  f32x4 acc[4][4];
#pragma unroll
  for (int i = 0; i < 4; ++i)
#pragma unroll
    for (int j = 0; j < 4; ++j) acc[i][j] = f32x4{0.f, 0.f, 0.f, 0.f};

  int wm = (wave & 1) * 64, wn = (wave >> 1) * 64;
  int quad = lane >> 4, r16 = lane & 15;

  auto stage = [&](int buf, int kb) {
#pragma unroll
    for (int r = 0; r < 2; ++r) {
      int row = r * 64 + ldRow;
      int gcol = kb + ((ldC - (row >> 1)) & 3) * 8;   // column swizzle
      gload_lds16(Aptr + (size_t)row * HID + gcol, &As[buf][wave * 512 + r * 2048]);
      gload_lds16(Bptr + (size_t)row * HID + gcol, &Bs[buf][wave * 512 + r * 2048]);
    }
  };

  if (tid < BM) { sTok[tid] = slotTok[row0 + tid]; sW[tid] = slotW[row0 + tid]; }

  stage(0, 0);
  for (int kb = 0; kb < HID; kb += BK) {
    int cur = (kb >> 5) & 1;
    asm volatile("s_waitcnt vmcnt(0)" ::: "memory");
    __syncthreads();
    if (kb + BK < HID) stage(cur ^ 1, kb + BK);
    bf16x8 af[4], bfr[4];
#pragma unroll
    for (int i = 0; i < 4; ++i) {
      int row = wm + i * 16 + r16;
      af[i] = *reinterpret_cast<const bf16x8*>(&As[cur][row * BK + ((quad + (row >> 1)) & 3) * 8]);
    }
#pragma unroll
    for (int j = 0; j < 4; ++j) {
      int row = wn + j * 16 + r16;
      bfr[j] = *reinterpret_cast<const bf16x8*>(&Bs[cur][row * BK + ((quad + (row >> 1)) & 3) * 8]);
    }
#pragma unroll
    for (int i = 0; i < 4; ++i)
#pragma unroll
      for (int j = 0; j < 4; ++j)
        acc[i][j] = __builtin_amdgcn_mfma_f32_16x16x32_bf16(af[i], bfr[j], acc[i][j], 0, 0, 0);
  }
#pragma unroll
  for (int j = 0; j < 4; ++j) {
    int gc = col0 + wn + j * 16 + r16;
    float bias = b2[(size_t)e * DIM + gc];
#pragma unroll
    for (int i = 0; i < 4; ++i)
#pragma unroll
      for (int r = 0; r < 4; ++r) {
        int lr = wm + i * 16 + quad * 4 + r;
        float v = (acc[i][j][r] + bias) * sW[lr];
        atomicAdd(&outF[(size_t)sTok[lr] * DIM + gc], v);
      }
  }
}

extern "C" void kernel_launch(void* const* d_in, const int* in_sizes, int n_in,
                              void* d_out, int out_size, void* d_ws, size_t ws_size,
                              hipStream_t stream)
{
  const float* x  = (const float*)d_in[0];
  const float* Wr = (const float*)d_in[1];
  const float* br = (const float*)d_in[2];
  const float* W1 = (const float*)d_in[3];
  const float* b1 = (const float*)d_in[4];
  const float* W2 = (const float*)d_in[5];
  const float* b2 = (const float*)d_in[6];
  float* outF = (float*)d_out;

  char* ws = (char*)d_ws;
  size_t off = 0;
  auto alloc = [&](size_t bytes) -> char* {
    char* p = ws + off; off += (bytes + 255) & ~(size_t)255; return p;
  };
  char* meta = alloc(4096);
  float* probs_sum = (float*)meta;
  int*   mask_count = (int*)(meta + 64);
  int*   offPad = (int*)(meta + 128);
  int2*  tokE = (int2*)alloc((size_t)N_TOK * 8);
  float2* tokW = (float2*)alloc((size_t)N_TOK * 8);
  int*   slotTok = (int*)alloc((size_t)MAXSLOT * 4);
  float* slotW = (float*)alloc((size_t)MAXSLOT * 4);
  unsigned short* Xg  = (unsigned short*)alloc((size_t)MAXSLOT * DIM * 2);
  unsigned short* W1t = (unsigned short*)alloc((size_t)NE * HID * DIM * 2);
  unsigned short* W2t = (unsigned short*)alloc((size_t)NE * DIM * HID * 2);
  size_t hFull = (size_t)MAXSLOT * HID * 2;
  size_t hOne  = (size_t)CAP * HID * 2;
  bool compact = (off + hFull) <= ws_size;
  unsigned short* Hbuf = (unsigned short*)alloc(compact ? hFull : hOne);

  hipMemsetAsync(meta, 0, 4096, stream);
  hipMemsetAsync(d_out, 0, (size_t)out_size * 4, stream);

  transpose_cvt<<<dim3(HID / 64, DIM / 64, NE), 256, 0, stream>>>(W1, W1t, DIM, HID);
  transpose_cvt<<<dim3(DIM / 64, HID / 64, NE), 256, 0, stream>>>(W2, W2t, HID, DIM);
  router_kernel<<<dim3(N_TOK / 8), 256, 0, stream>>>(x, Wr, br, tokE, tokW, probs_sum, mask_count);
  scan_kernel<<<dim3(1), 512, 0, stream>>>(tokE, tokW, mask_count, offPad, slotTok, slotW);
  aux_kernel<<<dim3(1), 64, 0, stream>>>(probs_sum, mask_count, outF + (size_t)N_TOK * DIM);
  gather_kernel<<<dim3(MAXSLOT / 4), 256, 0, stream>>>(x, slotTok, offPad, Xg);

  if (compact) {
    gemm1_kernel<<<dim3(HID / BN, CAP / BM, NE), 256, 0, stream>>>(Xg, W1t, b1, offPad, Hbuf, 0, 1);
    gemm2_kernel<<<dim3(DIM / BN, CAP / BM, NE), 256, 0, stream>>>(Hbuf, W2t, b2, offPad, slotTok, slotW, outF, 0, 1);
  } else {
    for (int e = 0; e < NE; ++e) {
      gemm1_kernel<<<dim3(HID / BN, CAP / BM, 1), 256, 0, stream>>>(Xg, W1t, b1, offPad, Hbuf, e, 0);
      gemm2_kernel<<<dim3(DIM / BN, CAP / BM, 1), 256, 0, stream>>>(Hbuf, W2t, b2, offPad, slotTok, slotW, outF, e, 0);
    }
  }
}